// Round 3
// baseline (102.864 us; speedup 1.0000x reference)
//
#include <hip/hip_runtime.h>
#include <hip/hip_bf16.h>

// CorrelationNetwork fused kernels for MI355X (gfx950) — round 7.
// R6 post-mortem: corr is LDS-read-bound: 40 ds_read_b128/tile/wave
// (~5.2 MB/CU = ~26us on the 85 B/cyc LDS pipe; MFMA needs only 2us).
// 32 of those 40 reads (W2 frags, Aj frags) are tile-invariant.
// R7: extract W2 (64 VGPR bf16) + Aj (64 VGPR f32) fragments from LDS ONCE
// per block; tile loop reads only Ai (lane-uniform broadcast) + b2/w3.
// Reg budget ~210 -> __launch_bounds__(512,2) (cap 256; R5's spill was the
// 128 cap, give 20% headroom). 1 block/CU either way, so grid = 256 blocks
// x 16 tiles: exactly one block per CU, staging done once.

typedef __bf16 bf16x8 __attribute__((ext_vector_type(8)));
typedef float f32x4 __attribute__((ext_vector_type(4)));

#define B_SZ 128
#define N_SZ 64
#define H_SZ 128

// ---- setup: blocks 0..2047 prepass (4 bn-rows each), 2048..2111 W2->W2T bf16,
//      block 2112 softmax(mixing_weights)   (unchanged — proven)
__global__ __launch_bounds__(256) void setup_kernel(
    const float* __restrict__ af, const float* __restrict__ W1,
    const float* __restrict__ b1, const float* __restrict__ W2,
    const float* __restrict__ mw, float* __restrict__ AiP,
    float* __restrict__ Aj, unsigned short* __restrict__ W2T,
    float* __restrict__ outw)
{
  const int blk = blockIdx.x;
  const int tid = threadIdx.x;

  if (blk < 2048) {
    // prepass: AiP[bn,h] = sum_f f[bn,f]*W1[f,h] + b1[h]; Aj via W1[64+f]
    __shared__ float fl[4 * 64];
    const int bn0 = blk << 2;
    fl[tid] = af[((bn0 + (tid >> 6)) << 7) + (tid & 63)];
    __syncthreads();
    const int h    = tid & 127;
    const int half = tid >> 7;                 // 0 -> Ai, 1 -> Aj
    const float* Wp = W1 + ((half << 6) << 7) + h;
    float acc0 = 0.f, acc1 = 0.f, acc2 = 0.f, acc3 = 0.f;
#pragma unroll
    for (int fq = 0; fq < 16; ++fq) {
      const float w0 = Wp[(fq * 4 + 0) << 7];
      const float w1v = Wp[(fq * 4 + 1) << 7];
      const float w2v = Wp[(fq * 4 + 2) << 7];
      const float w3v = Wp[(fq * 4 + 3) << 7];
      const float4 f0 = *(const float4*)&fl[0 * 64 + (fq << 2)];
      const float4 f1 = *(const float4*)&fl[1 * 64 + (fq << 2)];
      const float4 f2 = *(const float4*)&fl[2 * 64 + (fq << 2)];
      const float4 f3 = *(const float4*)&fl[3 * 64 + (fq << 2)];
      acc0 = fmaf(f0.x, w0, fmaf(f0.y, w1v, fmaf(f0.z, w2v, fmaf(f0.w, w3v, acc0))));
      acc1 = fmaf(f1.x, w0, fmaf(f1.y, w1v, fmaf(f1.z, w2v, fmaf(f1.w, w3v, acc1))));
      acc2 = fmaf(f2.x, w0, fmaf(f2.y, w1v, fmaf(f2.z, w2v, fmaf(f2.w, w3v, acc2))));
      acc3 = fmaf(f3.x, w0, fmaf(f3.y, w1v, fmaf(f3.z, w2v, fmaf(f3.w, w3v, acc3))));
    }
    if (half == 0) {
      const float bb = b1[h];
      AiP[((bn0 + 0) << 7) + h] = acc0 + bb;
      AiP[((bn0 + 1) << 7) + h] = acc1 + bb;
      AiP[((bn0 + 2) << 7) + h] = acc2 + bb;
      AiP[((bn0 + 3) << 7) + h] = acc3 + bb;
    } else {
      Aj[((bn0 + 0) << 7) + h] = acc0;
      Aj[((bn0 + 1) << 7) + h] = acc1;
      Aj[((bn0 + 2) << 7) + h] = acc2;
      Aj[((bn0 + 3) << 7) + h] = acc3;
    }
  } else if (blk < 2112) {
    // W2 (128x128, k-major) -> W2T (n-major) bf16
    int idx = ((blk - 2048) << 8) + tid;       // 0..16383
    int k = idx >> 7, n = idx & 127;
    unsigned u = __float_as_uint(W2[idx]);
    u += 0x7fffu + ((u >> 16) & 1u);
    W2T[(n << 7) + k] = (unsigned short)(u >> 16);
  } else {
    // softmax over 64 mixing weights
    if (tid < 64) {
      float v = mw[tid];
      float m = v;
      for (int off = 32; off > 0; off >>= 1) m = fmaxf(m, __shfl_xor(m, off));
      float e = expf(v - m);
      float s = e;
      for (int off = 32; off > 0; off >>= 1) s += __shfl_xor(s, off);
      outw[tid] = e / s;
    }
  }
}

// ---- main kernel: 256 blocks x 512 thr (1/CU), block = (b, half), 16 tiles.
// Wave: wm = wave&1 (w2col half), wn = wave>>1 (row quarter, 32 rows).
// W2 frags (64 VGPR) and Aj frags (64 VGPR) extracted from LDS once; tile
// loop reads LDS only for Ai (lane-uniform broadcast) and b2/w3.
__global__ __launch_bounds__(512, 2) void corr_kernel(
    const float* __restrict__ AiP, const float* __restrict__ Aj,
    const unsigned short* __restrict__ W2T,
    const float* __restrict__ b2, const float* __restrict__ w3,
    const float* __restrict__ b3, float* __restrict__ out)
{
  __shared__ __align__(16) unsigned short W2s[128 * 128];  // 32 KB, swizzled
  __shared__ __align__(16) float AjF[64 * 132];            // 33.8 KB, pad-132
  __shared__ __align__(16) float AiF[32 * 132];            // 16.9 KB
  __shared__ float b2s[128], w3s[128];
  __shared__ float part[2][2][128];                        // [tile&1][wm][row]

  const int tid  = threadIdx.x;
  const int lane = tid & 63;
  const int wave = tid >> 6;            // 0..7
  const int c = lane & 15, g = lane >> 4;
  const int wm = wave & 1;              // w2col half (64 cols)
  const int wn = wave >> 1;             // row quarter (32 rows)

  const int blk = blockIdx.x;
  const int b   = blk >> 1;             // 0..127
  const int ih  = blk & 1;              // i-half: 16 i-pairs each
  const int ip0 = ih << 4;

  // ---- stage W2T -> W2s swizzled, once per block (coalesced)
  {
    const uint4* src = (const uint4*)W2T;     // 2048 x 16B chunks
#pragma unroll
    for (int it = 0; it < 4; ++it) {
      const int idx = (it << 9) + tid;        // 0..2047
      const int n = idx >> 4, e = idx & 15;
      const uint4 v = src[idx];
      *(uint4*)&W2s[(n << 7) + ((e ^ (n & 15)) << 3)] = v;
    }
  }
  // ---- stage Aj (64 rows), Ai (32 rows), b2/w3 — once per block, coalesced
  {
    const float4* src = (const float4*)(Aj + (b << 13));
#pragma unroll
    for (int p = 0; p < 4; ++p) {
      const int idx = (p << 9) + tid;         // 0..2047 float4s
      const int r = idx >> 5, u = idx & 31;
      *(float4*)&AjF[r * 132 + (u << 2)] = src[idx];
    }
    const float4* srcA = (const float4*)(AiP + (((b << 6) + (ih << 5)) << 7));
#pragma unroll
    for (int p = 0; p < 2; ++p) {
      const int idx = (p << 9) + tid;         // 0..1023 float4s
      const int r = idx >> 5, u = idx & 31;
      *(float4*)&AiF[r * 132 + (u << 2)] = srcA[idx];
    }
    if (tid < 128) b2s[tid] = b2[tid];
    else if (tid < 256) w3s[tid - 128] = w3[tid - 128];
  }

  const float bias3 = b3[0];
  const int i_sel = wn >> 1;                  // row>=64 -> second i of pair

  __syncthreads();

  // ---- extract tile-invariant fragments to registers (once per block)
  // W2 A-frag lane(c,g): m = wm*64 + mt*16 + c, k = kt*32 + g*8 + e.
  bf16x8 w2r[4][4];
#pragma unroll
  for (int mt = 0; mt < 4; ++mt)
#pragma unroll
    for (int kt = 0; kt < 4; ++kt) {
      const int es = ((kt << 2) + g) ^ c;
      w2r[mt][kt] = *(const bf16x8*)&W2s[(((wm << 6) + (mt << 4) + c) << 7) + (es << 3)];
    }
  // Aj B-frag rows: j = wn*32 + tn*16 + c; cols kt*32 + g*8 + 0..7 (f32)
  f32x4 ajr[4][2][2];
#pragma unroll
  for (int kt = 0; kt < 4; ++kt)
#pragma unroll
    for (int tn = 0; tn < 2; ++tn) {
      const int j = ((wn << 5) + (tn << 4) + c) & 63;
      const float* ajb = &AjF[j * 132 + (g << 3) + (kt << 5)];
      ajr[kt][tn][0] = *(const f32x4*)(ajb);
      ajr[kt][tn][1] = *(const f32x4*)(ajb + 4);
    }

  for (int t = 0; t < 16; ++t) {
    const float* aib = &AiF[((t << 1) + i_sel) * 132 + (g << 3)];

    // ---- MFMA: acc init = b2 (D = A*B + C)
    f32x4 acc[4][2];
#pragma unroll
    for (int mt = 0; mt < 4; ++mt) {
      const f32x4 bv = *(const f32x4*)&b2s[(wm << 6) + (mt << 4) + (g << 2)];
      acc[mt][0] = bv;
      acc[mt][1] = bv;
    }

#pragma unroll
    for (int kt = 0; kt < 4; ++kt) {
      // Ai row is wave-uniform -> LDS broadcast read (conflict-free)
      const f32x4 a0 = *(const f32x4*)(aib + (kt << 5));
      const f32x4 a1 = *(const f32x4*)(aib + (kt << 5) + 4);
      bf16x8 hv[2];
#pragma unroll
      for (int tn = 0; tn < 2; ++tn) {
        const f32x4 h0 = a0 + ajr[kt][tn][0];
        const f32x4 h1v = a1 + ajr[kt][tn][1];
#pragma unroll
        for (int e = 0; e < 4; ++e) {
          hv[tn][e]     = (__bf16)fmaxf(h0[e], 0.f);
          hv[tn][e + 4] = (__bf16)fmaxf(h1v[e], 0.f);
        }
      }
#pragma unroll
      for (int mt = 0; mt < 4; ++mt)
#pragma unroll
        for (int tn = 0; tn < 2; ++tn)
          acc[mt][tn] = __builtin_amdgcn_mfma_f32_16x16x32_bf16(
              w2r[mt][kt], hv[tn], acc[mt][tn], 0, 0, 0);
    }

    // ---- epilogue: relu(h2).w3 in-lane over (mt,p), shfl over g, LDS over wm
    float s0 = 0.f, s1 = 0.f;
#pragma unroll
    for (int mt = 0; mt < 4; ++mt) {
      const f32x4 wv3 = *(const f32x4*)&w3s[(wm << 6) + (mt << 4) + (g << 2)];
#pragma unroll
      for (int p = 0; p < 4; ++p) {
        s0 = fmaf(fmaxf(acc[mt][0][p], 0.f), wv3[p], s0);
        s1 = fmaf(fmaxf(acc[mt][1][p], 0.f), wv3[p], s1);
      }
    }
    s0 += __shfl_xor(s0, 16);
    s0 += __shfl_xor(s0, 32);
    s1 += __shfl_xor(s1, 16);
    s1 += __shfl_xor(s1, 32);

    const int pb = t & 1;
    if (g == 0) {                              // 16 lanes, conflict-free
      part[pb][wm][(wn << 5) + c]      = s0;
      part[pb][wm][(wn << 5) + 16 + c] = s1;
    }

    __syncthreads();                           // ONE barrier per tile

    if (tid < 128) {
      const float v = part[pb][0][tid] + part[pb][1][tid] + bias3;
      out[(b << 12) + ((ip0 + t) << 7) + tid] = 1.f / (1.f + __expf(-v));
    }
  }
}

extern "C" void kernel_launch(void* const* d_in, const int* in_sizes, int n_in,
                              void* d_out, int out_size, void* d_ws,
                              size_t ws_size, hipStream_t stream)
{
  const float* af = (const float*)d_in[0];   // (128,64,128)
  const float* W1 = (const float*)d_in[1];   // (128,128)
  const float* b1 = (const float*)d_in[2];   // (128,)
  const float* W2 = (const float*)d_in[3];   // (128,128)
  const float* b2 = (const float*)d_in[4];   // (128,)
  const float* w3 = (const float*)d_in[5];   // (128,)
  const float* b3 = (const float*)d_in[6];   // (1,)
  const float* mw = (const float*)d_in[7];   // (64,)
  float* out = (float*)d_out;                // 524288 corr + 64 weights

  float* AiP = (float*)d_ws;                           // 4 MB
  float* Aj  = AiP + B_SZ * N_SZ * H_SZ;               // 4 MB
  unsigned short* W2T = (unsigned short*)(Aj + B_SZ * N_SZ * H_SZ);  // 32 KB

  setup_kernel<<<2113, 256, 0, stream>>>(af, W1, b1, W2, mw, AiP, Aj, W2T,
                                         out + B_SZ * N_SZ * N_SZ);
  // 256 blocks (1/CU), each owns (b, i-half) = 16 tiles
  corr_kernel<<<256, 512, 0, stream>>>(AiP, Aj, W2T, b2, w3, b3, out);
}